// Round 9
// baseline (36.002 us; speedup 1.0000x reference)
//
#include <hip/hip_runtime.h>

// Problem constants
#define HDIM 2048
#define NUM_V 32
#define NUM_K 16
#define DK 128
#define DV 128
#define KEY_DIM 2048          // NUM_K*DK
#define VALUE_DIM 4096        // NUM_V*DV
#define CONV_DIM 8192         // 2*KEY_DIM+VALUE_DIM
#define TOTAL_ROWS 12352      // 8192 + 4096 + 32 + 32
#define K1_WAVES 3088         // persistent waves: 772 blocks x 4 waves
#define K1_PAIRS (TOTAL_ROWS / 2)   // 6176 row-pairs, 2 per wave

// ws layout (floats):
//  [0,      8192)  conv_out   (q | k | v)
//  [8192,  12288)  z
//  [12288, 12320)  b
//  [12320, 12352)  a
//  [12352, 16448)  out_vec (4096)

// d_out layout (floats): [0,2048) hidden_out | [2048,34816) new_conv_state (8192x4)
//                        | [34816, 559104) rec (32x128x128)

typedef __attribute__((ext_vector_type(4))) float f32x4;

// ---------------- Kernel 1: fused GEMV (W_qkv | W_z | W_b | W_a) @ h ----------
// Persistent waves; h held in 32 VGPRs (8 x f32x4 per lane) -> inner loop is a
// pure weight stream: 8 dwordx4 + 32 FMA per row, no h reloads.
__global__ __launch_bounds__(256) void k1_gemv(
    const float* __restrict__ h,          // 2048
    const float* __restrict__ Wqkv,       // 8192 x 2048
    const float* __restrict__ Wz,         // 4096 x 2048
    const float* __restrict__ Wb,         // 32 x 2048
    const float* __restrict__ Wa,         // 32 x 2048
    const float* __restrict__ conv_state, // 8192 x 4
    const float* __restrict__ conv_w,     // 8192 x 4
    float* __restrict__ ws,
    float* __restrict__ out_conv)         // d_out + 2048 : 8192 x 4
{
    const int lane  = threadIdx.x & 63;
    const int gwave = (blockIdx.x * 256 + threadIdx.x) >> 6;   // 0..3087

    // preload h: lane covers columns (i*64+lane)*4 .. +3
    f32x4 hreg[8];
#pragma unroll
    for (int i = 0; i < 8; ++i)
        hreg[i] = *reinterpret_cast<const f32x4*>(h + (i * 64 + lane) * 4);

    for (int pair = gwave; pair < K1_PAIRS; pair += K1_WAVES) {
        const int row0 = pair * 2;        // region boundaries even -> uniform pair

        const float* w0;
        if (row0 < 8192)       w0 = Wqkv + (size_t)row0 * HDIM;
        else if (row0 < 12288) w0 = Wz   + (size_t)(row0 - 8192) * HDIM;
        else if (row0 < 12320) w0 = Wb   + (size_t)(row0 - 12288) * HDIM;
        else                   w0 = Wa   + (size_t)(row0 - 12320) * HDIM;
        const float* w1 = w0 + HDIM;

        float acc0 = 0.f, acc1 = 0.f;
#pragma unroll
        for (int i = 0; i < 8; ++i) {
            const int idx = (i * 64 + lane) * 4;
            f32x4 a4 = *reinterpret_cast<const f32x4*>(w0 + idx);
            f32x4 b4 = *reinterpret_cast<const f32x4*>(w1 + idx);
            acc0 += a4.x * hreg[i].x + a4.y * hreg[i].y + a4.z * hreg[i].z + a4.w * hreg[i].w;
            acc1 += b4.x * hreg[i].x + b4.y * hreg[i].y + b4.z * hreg[i].z + b4.w * hreg[i].w;
        }
#pragma unroll
        for (int off = 32; off > 0; off >>= 1) {
            acc0 += __shfl_down(acc0, off, 64);
            acc1 += __shfl_down(acc1, off, 64);
        }

        if (lane == 0) {
            if (row0 < 8192) {
                f32x4 cs0 = *reinterpret_cast<const f32x4*>(conv_state + row0 * 4);
                f32x4 cw0 = *reinterpret_cast<const f32x4*>(conv_w + row0 * 4);
                f32x4 cs1 = *reinterpret_cast<const f32x4*>(conv_state + row0 * 4 + 4);
                f32x4 cw1 = *reinterpret_cast<const f32x4*>(conv_w + row0 * 4 + 4);
                float pre0 = cs0.y * cw0.x + cs0.z * cw0.y + cs0.w * cw0.z + acc0 * cw0.w;
                float pre1 = cs1.y * cw1.x + cs1.z * cw1.y + cs1.w * cw1.z + acc1 * cw1.w;
                ws[row0]     = pre0 / (1.f + expf(-pre0));   // silu -> conv_out
                ws[row0 + 1] = pre1 / (1.f + expf(-pre1));
                f32x4 n0; n0.x = cs0.y; n0.y = cs0.z; n0.z = cs0.w; n0.w = acc0;
                f32x4 n1; n1.x = cs1.y; n1.y = cs1.z; n1.z = cs1.w; n1.w = acc1;
                *reinterpret_cast<f32x4*>(out_conv + row0 * 4)     = n0;
                *reinterpret_cast<f32x4*>(out_conv + row0 * 4 + 4) = n1;
            } else {
                ws[row0]     = acc0;   // z | b | a
                ws[row0 + 1] = acc1;
            }
        }
    }
}

// ---------------- Kernel 2: per-head recurrent state update --------------------
// (R8-proven: registers hold rec rows between pass 1 and pass 2)
__global__ __launch_bounds__(1024) void k2_rec(
    const float* __restrict__ ws,        // conv_out | z | b | a
    const float* __restrict__ rec_in,    // 32 x 128 x 128
    const float* __restrict__ dt_bias,   // 32
    const float* __restrict__ A_log,     // 32
    const float* __restrict__ norm_w,    // 128
    float* __restrict__ rec_out,         // d_out + 34816
    float* __restrict__ out_vec)         // ws + 12352 (4096 f32)
{
    __shared__ float s_k[128];
    __shared__ float s_q[128];
    __shared__ float s_delta[128];
    __shared__ float s_part[8][128];
    __shared__ float s_red[4];

    const int hh  = blockIdx.x;      // head 0..31
    const int t   = threadIdx.x;     // 0..1023
    const int d   = t & 127;         // column
    const int kkb = t >> 7;          // 0..7 : owns kk in [kkb*16, kkb*16+16)
    const int kh  = hh >> 1;         // key head (VPK = 2)

    const float bv    = ws[12288 + hh];
    const float av    = ws[12320 + hh];
    const float beta  = 1.f / (1.f + expf(-bv));
    const float x     = av + dt_bias[hh];
    const float sp    = fmaxf(x, 0.f) + log1pf(expf(-fabsf(x)));   // softplus
    const float decay = expf(-expf(A_log[hh]) * sp);

    float qr = 0.f, kr = 0.f;
    if (t < 128) {
        qr = ws[kh * 128 + d];
        kr = ws[KEY_DIM + kh * 128 + d];
        float sq = qr * qr, sk = kr * kr;
#pragma unroll
        for (int off = 32; off > 0; off >>= 1) {
            sq += __shfl_down(sq, off, 64);
            sk += __shfl_down(sk, off, 64);
        }
        if ((t & 63) == 0) { s_red[t >> 6] = sq; s_red[2 + (t >> 6)] = sk; }
    }
    __syncthreads();
    if (t < 128) {
        const float ssq = s_red[0] + s_red[1];
        const float ssk = s_red[2] + s_red[3];
        s_q[d] = qr * rsqrtf(ssq + 1e-6f) * 0.08838834764831845f;  // l2norm * 1/sqrt(DK)
        s_k[d] = kr * rsqrtf(ssk + 1e-6f);
    }
    __syncthreads();

    const float* rrow = rec_in  + (size_t)hh * (DK * DV) + kkb * 16 * DV;
    float*       wrow = rec_out + (size_t)hh * (DK * DV) + kkb * 16 * DV;

    float rv[16];
#pragma unroll
    for (int i = 0; i < 16; ++i)
        rv[i] = rrow[i * DV + d];

    float kvp = 0.f;
#pragma unroll
    for (int i = 0; i < 16; ++i)
        kvp += rv[i] * s_k[kkb * 16 + i];
    s_part[kkb][d] = kvp;
    __syncthreads();

    if (t < 128) {
        float kv = 0.f;
#pragma unroll
        for (int j = 0; j < 8; ++j) kv += s_part[j][d];
        kv *= decay;
        const float vv = ws[2 * KEY_DIM + hh * 128 + d];
        s_delta[d] = (vv - kv) * beta;
    }
    __syncthreads();

    const float dlt = s_delta[d];
    float corep = 0.f;
#pragma unroll
    for (int i = 0; i < 16; ++i) {
        const float r = rv[i] * decay + s_k[kkb * 16 + i] * dlt;
        wrow[i * DV + d] = r;
        corep += r * s_q[kkb * 16 + i];
    }
    s_part[kkb][d] = corep;
    __syncthreads();

    float core = 0.f;
    if (t < 128) {
#pragma unroll
        for (int j = 0; j < 8; ++j) core += s_part[j][d];
        float sc = core * core;
#pragma unroll
        for (int off = 32; off > 0; off >>= 1)
            sc += __shfl_down(sc, off, 64);
        if ((t & 63) == 0) s_red[t >> 6] = sc;
    }
    __syncthreads();
    if (t < 128) {
        const float ssc = s_red[0] + s_red[1];
        const float xn  = core * rsqrtf(ssc * (1.f / 128.f) + 1e-6f) * norm_w[d];
        const float zv  = ws[8192 + hh * 128 + d];
        out_vec[hh * 128 + d] = xn * (zv / (1.f + expf(-zv)));   // xn * silu(z)
    }
}

// ---------------- Kernel 3: hidden_out = W_out @ out_vec ----------------------
// TWO rows per wave (shared out_vec loads), plain loads (no nt).
__global__ __launch_bounds__(256) void k3_out(
    const float* __restrict__ Wout,       // 2048 x 4096
    const float* __restrict__ out_vec,    // 4096 f32
    float* __restrict__ hidden_out)       // d_out[0:2048]
{
    const int pair = (blockIdx.x * 256 + threadIdx.x) >> 6;   // 0..1023
    const int lane = threadIdx.x & 63;
    if (pair >= HDIM / 2) return;
    const int row0 = pair * 2;

    const float* w0 = Wout + (size_t)row0 * VALUE_DIM;
    const float* w1 = w0 + VALUE_DIM;

    float acc0 = 0.f, acc1 = 0.f;
#pragma unroll
    for (int i = 0; i < 16; ++i) {
        const int idx = (i * 64 + lane) * 4;
        f32x4 o4 = *reinterpret_cast<const f32x4*>(out_vec + idx);
        f32x4 a4 = *reinterpret_cast<const f32x4*>(w0 + idx);
        f32x4 b4 = *reinterpret_cast<const f32x4*>(w1 + idx);
        acc0 += a4.x * o4.x + a4.y * o4.y + a4.z * o4.z + a4.w * o4.w;
        acc1 += b4.x * o4.x + b4.y * o4.y + b4.z * o4.z + b4.w * o4.w;
    }
#pragma unroll
    for (int off = 32; off > 0; off >>= 1) {
        acc0 += __shfl_down(acc0, off, 64);
        acc1 += __shfl_down(acc1, off, 64);
    }
    if (lane == 0) {
        hidden_out[row0]     = acc0;
        hidden_out[row0 + 1] = acc1;
    }
}

extern "C" void kernel_launch(void* const* d_in, const int* in_sizes, int n_in,
                              void* d_out, int out_size, void* d_ws, size_t ws_size,
                              hipStream_t stream) {
    const float* hidden_in  = (const float*)d_in[0];
    const float* conv_state = (const float*)d_in[1];
    const float* rec_state  = (const float*)d_in[2];
    const float* W_qkv      = (const float*)d_in[3];
    const float* W_z        = (const float*)d_in[4];
    const float* W_b        = (const float*)d_in[5];
    const float* W_a        = (const float*)d_in[6];
    const float* W_out      = (const float*)d_in[7];
    const float* conv_w     = (const float*)d_in[8];
    const float* dt_bias    = (const float*)d_in[9];
    const float* A_log      = (const float*)d_in[10];
    const float* norm_w     = (const float*)d_in[11];

    float* out = (float*)d_out;
    float* ws  = (float*)d_ws;

    // out layout (f32): [0,2048) hidden_out | [2048,34816) new_conv_state | [34816,...) rec
    k1_gemv<<<K1_WAVES / 4, 256, 0, stream>>>(hidden_in, W_qkv, W_z, W_b, W_a,
                                              conv_state, conv_w, ws, out + 2048);
    k2_rec<<<NUM_V, 1024, 0, stream>>>(ws, rec_state, dt_bias, A_log, norm_w,
                                       out + 2048 + CONV_DIM * 4, ws + 12352);
    k3_out<<<(HDIM / 2) / 4, 256, 0, stream>>>(W_out, ws + 12352, out);
}

// Round 10
// 33.933 us; speedup vs baseline: 1.0610x; 1.0610x over previous
//
#include <hip/hip_runtime.h>

// Problem constants
#define HDIM 2048
#define NUM_V 32
#define NUM_K 16
#define DK 128
#define DV 128
#define KEY_DIM 2048          // NUM_K*DK
#define VALUE_DIM 4096        // NUM_V*DV
#define CONV_DIM 8192         // 2*KEY_DIM+VALUE_DIM
#define TOTAL_ROWS 12352      // 8192 + 4096 + 32 + 32

// ws layout (floats):
//  [0,      8192)  conv_out   (q | k | v)
//  [8192,  12288)  z
//  [12288, 12320)  b
//  [12320, 12352)  a
//  [12352, 16448)  out_vec (4096)

// d_out layout (floats): [0,2048) hidden_out | [2048,34816) new_conv_state (8192x4)
//                        | [34816, 559104) rec (32x128x128)

typedef __attribute__((ext_vector_type(4))) float f32x4;

// ---------------- Kernel 1: fused GEMV (W_qkv | W_z | W_b | W_a) @ h ----------
// 1024-thread blocks (16 waves), 1 row/wave (full 12352-wave TLP, 32 waves/CU).
// h staged in LDS once per block -> VMEM path carries ONLY the weight stream;
// h re-reads go through the LDS pipe (ds_read_b128).
__global__ __launch_bounds__(1024) void k1_gemv(
    const float* __restrict__ h,          // 2048
    const float* __restrict__ Wqkv,       // 8192 x 2048
    const float* __restrict__ Wz,         // 4096 x 2048
    const float* __restrict__ Wb,         // 32 x 2048
    const float* __restrict__ Wa,         // 32 x 2048
    const float* __restrict__ conv_state, // 8192 x 4
    const float* __restrict__ conv_w,     // 8192 x 4
    float* __restrict__ ws,
    float* __restrict__ out_conv)         // d_out + 2048 : 8192 x 4
{
    __shared__ f32x4 s_h[512];            // 8 KB: h staged once per block

    const int t    = threadIdx.x;
    const int lane = t & 63;
    const int wid  = t >> 6;              // 0..15

    if (t < 512)
        s_h[t] = *reinterpret_cast<const f32x4*>(h + t * 4);
    __syncthreads();

    const int row = blockIdx.x * 16 + wid;    // 772 blocks x 16 waves = 12352 rows

    const float* wrow;
    if (row < 8192)       wrow = Wqkv + (size_t)row * HDIM;
    else if (row < 12288) wrow = Wz   + (size_t)(row - 8192) * HDIM;
    else if (row < 12320) wrow = Wb   + (size_t)(row - 12288) * HDIM;
    else                  wrow = Wa   + (size_t)(row - 12320) * HDIM;

    float acc = 0.f;
#pragma unroll
    for (int i = 0; i < 8; ++i) {
        f32x4 w4 = *reinterpret_cast<const f32x4*>(wrow + (i * 64 + lane) * 4);
        f32x4 h4 = s_h[i * 64 + lane];
        acc += w4.x * h4.x + w4.y * h4.y + w4.z * h4.z + w4.w * h4.w;
    }
#pragma unroll
    for (int off = 32; off > 0; off >>= 1)
        acc += __shfl_down(acc, off, 64);

    if (lane == 0) {
        if (row < 8192) {
            f32x4 cs = *reinterpret_cast<const f32x4*>(conv_state + row * 4);
            f32x4 cw = *reinterpret_cast<const f32x4*>(conv_w + row * 4);
            float pre = cs.y * cw.x + cs.z * cw.y + cs.w * cw.z + acc * cw.w;
            ws[row] = pre / (1.f + expf(-pre));     // silu -> conv_out
            f32x4 n; n.x = cs.y; n.y = cs.z; n.z = cs.w; n.w = acc;
            *reinterpret_cast<f32x4*>(out_conv + row * 4) = n;
        } else {
            ws[row] = acc;   // z / b / a land contiguously by construction
        }
    }
}

// ---------------- Kernel 2: per-head recurrent state update --------------------
// (R8-proven: registers hold rec rows between pass 1 and pass 2)
__global__ __launch_bounds__(1024) void k2_rec(
    const float* __restrict__ ws,        // conv_out | z | b | a
    const float* __restrict__ rec_in,    // 32 x 128 x 128
    const float* __restrict__ dt_bias,   // 32
    const float* __restrict__ A_log,     // 32
    const float* __restrict__ norm_w,    // 128
    float* __restrict__ rec_out,         // d_out + 34816
    float* __restrict__ out_vec)         // ws + 12352 (4096 f32)
{
    __shared__ float s_k[128];
    __shared__ float s_q[128];
    __shared__ float s_delta[128];
    __shared__ float s_part[8][128];
    __shared__ float s_red[4];

    const int hh  = blockIdx.x;      // head 0..31
    const int t   = threadIdx.x;     // 0..1023
    const int d   = t & 127;         // column
    const int kkb = t >> 7;          // 0..7 : owns kk in [kkb*16, kkb*16+16)
    const int kh  = hh >> 1;         // key head (VPK = 2)

    const float bv    = ws[12288 + hh];
    const float av    = ws[12320 + hh];
    const float beta  = 1.f / (1.f + expf(-bv));
    const float x     = av + dt_bias[hh];
    const float sp    = fmaxf(x, 0.f) + log1pf(expf(-fabsf(x)));   // softplus
    const float decay = expf(-expf(A_log[hh]) * sp);

    float qr = 0.f, kr = 0.f;
    if (t < 128) {
        qr = ws[kh * 128 + d];
        kr = ws[KEY_DIM + kh * 128 + d];
        float sq = qr * qr, sk = kr * kr;
#pragma unroll
        for (int off = 32; off > 0; off >>= 1) {
            sq += __shfl_down(sq, off, 64);
            sk += __shfl_down(sk, off, 64);
        }
        if ((t & 63) == 0) { s_red[t >> 6] = sq; s_red[2 + (t >> 6)] = sk; }
    }
    __syncthreads();
    if (t < 128) {
        const float ssq = s_red[0] + s_red[1];
        const float ssk = s_red[2] + s_red[3];
        s_q[d] = qr * rsqrtf(ssq + 1e-6f) * 0.08838834764831845f;  // l2norm * 1/sqrt(DK)
        s_k[d] = kr * rsqrtf(ssk + 1e-6f);
    }
    __syncthreads();

    const float* rrow = rec_in  + (size_t)hh * (DK * DV) + kkb * 16 * DV;
    float*       wrow = rec_out + (size_t)hh * (DK * DV) + kkb * 16 * DV;

    float rv[16];
#pragma unroll
    for (int i = 0; i < 16; ++i)
        rv[i] = rrow[i * DV + d];

    float kvp = 0.f;
#pragma unroll
    for (int i = 0; i < 16; ++i)
        kvp += rv[i] * s_k[kkb * 16 + i];
    s_part[kkb][d] = kvp;
    __syncthreads();

    if (t < 128) {
        float kv = 0.f;
#pragma unroll
        for (int j = 0; j < 8; ++j) kv += s_part[j][d];
        kv *= decay;
        const float vv = ws[2 * KEY_DIM + hh * 128 + d];
        s_delta[d] = (vv - kv) * beta;
    }
    __syncthreads();

    const float dlt = s_delta[d];
    float corep = 0.f;
#pragma unroll
    for (int i = 0; i < 16; ++i) {
        const float r = rv[i] * decay + s_k[kkb * 16 + i] * dlt;
        wrow[i * DV + d] = r;
        corep += r * s_q[kkb * 16 + i];
    }
    s_part[kkb][d] = corep;
    __syncthreads();

    float core = 0.f;
    if (t < 128) {
#pragma unroll
        for (int j = 0; j < 8; ++j) core += s_part[j][d];
        float sc = core * core;
#pragma unroll
        for (int off = 32; off > 0; off >>= 1)
            sc += __shfl_down(sc, off, 64);
        if ((t & 63) == 0) s_red[t >> 6] = sc;
    }
    __syncthreads();
    if (t < 128) {
        const float ssc = s_red[0] + s_red[1];
        const float xn  = core * rsqrtf(ssc * (1.f / 128.f) + 1e-6f) * norm_w[d];
        const float zv  = ws[8192 + hh * 128 + d];
        out_vec[hh * 128 + d] = xn * (zv / (1.f + expf(-zv)));   // xn * silu(z)
    }
}

// ---------------- Kernel 3: hidden_out = W_out @ out_vec ----------------------
// one wave per row (R3/R8-proven geometry).
__global__ __launch_bounds__(256) void k3_out(
    const float* __restrict__ Wout,       // 2048 x 4096
    const float* __restrict__ out_vec,    // 4096 f32
    float* __restrict__ hidden_out)       // d_out[0:2048]
{
    const int row  = (blockIdx.x * 256 + threadIdx.x) >> 6;
    const int lane = threadIdx.x & 63;
    if (row >= HDIM) return;

    const float* wrow = Wout + (size_t)row * VALUE_DIM;
    float acc = 0.f;
#pragma unroll
    for (int i = 0; i < 16; ++i) {
        const int idx = (i * 64 + lane) * 4;
        f32x4 w4 = *reinterpret_cast<const f32x4*>(wrow + idx);
        f32x4 o4 = *reinterpret_cast<const f32x4*>(out_vec + idx);
        acc += w4.x * o4.x + w4.y * o4.y + w4.z * o4.z + w4.w * o4.w;
    }
#pragma unroll
    for (int off = 32; off > 0; off >>= 1)
        acc += __shfl_down(acc, off, 64);
    if (lane == 0) hidden_out[row] = acc;
}

extern "C" void kernel_launch(void* const* d_in, const int* in_sizes, int n_in,
                              void* d_out, int out_size, void* d_ws, size_t ws_size,
                              hipStream_t stream) {
    const float* hidden_in  = (const float*)d_in[0];
    const float* conv_state = (const float*)d_in[1];
    const float* rec_state  = (const float*)d_in[2];
    const float* W_qkv      = (const float*)d_in[3];
    const float* W_z        = (const float*)d_in[4];
    const float* W_b        = (const float*)d_in[5];
    const float* W_a        = (const float*)d_in[6];
    const float* W_out      = (const float*)d_in[7];
    const float* conv_w     = (const float*)d_in[8];
    const float* dt_bias    = (const float*)d_in[9];
    const float* A_log      = (const float*)d_in[10];
    const float* norm_w     = (const float*)d_in[11];

    float* out = (float*)d_out;
    float* ws  = (float*)d_ws;

    // out layout (f32): [0,2048) hidden_out | [2048,34816) new_conv_state | [34816,...) rec
    k1_gemv<<<TOTAL_ROWS / 16, 1024, 0, stream>>>(hidden_in, W_qkv, W_z, W_b, W_a,
                                                  conv_state, conv_w, ws, out + 2048);
    k2_rec<<<NUM_V, 1024, 0, stream>>>(ws, rec_state, dt_bias, A_log, norm_w,
                                       out + 2048 + CONV_DIM * 4, ws + 12352);
    k3_out<<<HDIM / 4, 256, 0, stream>>>(W_out, ws + 12352, out);
}

// Round 11
// 33.821 us; speedup vs baseline: 1.0645x; 1.0033x over previous
//
#include <hip/hip_runtime.h>

// Problem constants
#define HDIM 2048
#define NUM_V 32
#define NUM_K 16
#define DK 128
#define DV 128
#define KEY_DIM 2048          // NUM_K*DK
#define VALUE_DIM 4096        // NUM_V*DV
#define CONV_DIM 8192         // 2*KEY_DIM+VALUE_DIM
#define TOTAL_ROWS 12352      // 8192 + 4096 + 32 + 32

// ws layout (floats):
//  [0,      8192)  conv_out   (q | k | v)
//  [8192,  12288)  z
//  [12288, 12320)  b
//  [12320, 12352)  a
//  [12352, 16448)  core (4096)   <- k2 writes un-normalized core; k3 normalizes
// d_out layout (floats): [0,2048) hidden_out | [2048,34816) new_conv_state (8192x4)
//                        | [34816, 559104) rec (32x128x128)

typedef __attribute__((ext_vector_type(4))) float f32x4;

// ---------------- Kernel 1: fused GEMV (W_qkv | W_z | W_b | W_a) @ h ----------
// one wave per row (R8-proven geometry, untouched).
__global__ __launch_bounds__(256) void k1_gemv(
    const float* __restrict__ h,
    const float* __restrict__ Wqkv,
    const float* __restrict__ Wz,
    const float* __restrict__ Wb,
    const float* __restrict__ Wa,
    const float* __restrict__ conv_state,
    const float* __restrict__ conv_w,
    float* __restrict__ ws,
    float* __restrict__ out_conv)
{
    const int row  = (blockIdx.x * 256 + threadIdx.x) >> 6;
    const int lane = threadIdx.x & 63;
    if (row >= TOTAL_ROWS) return;

    const float* wrow;
    if (row < 8192)       wrow = Wqkv + (size_t)row * HDIM;
    else if (row < 12288) wrow = Wz   + (size_t)(row - 8192) * HDIM;
    else if (row < 12320) wrow = Wb   + (size_t)(row - 12288) * HDIM;
    else                  wrow = Wa   + (size_t)(row - 12320) * HDIM;

    float acc = 0.f;
#pragma unroll
    for (int i = 0; i < 8; ++i) {
        const int idx = (i * 64 + lane) * 4;
        f32x4 w4 = *reinterpret_cast<const f32x4*>(wrow + idx);
        f32x4 h4 = *reinterpret_cast<const f32x4*>(h + idx);
        acc += w4.x * h4.x + w4.y * h4.y + w4.z * h4.z + w4.w * h4.w;
    }
#pragma unroll
    for (int off = 32; off > 0; off >>= 1)
        acc += __shfl_down(acc, off, 64);

    if (lane == 0) {
        if (row < 8192) {
            f32x4 cs = *reinterpret_cast<const f32x4*>(conv_state + row * 4);
            f32x4 cw = *reinterpret_cast<const f32x4*>(conv_w + row * 4);
            float pre = cs.y * cw.x + cs.z * cw.y + cs.w * cw.z + acc * cw.w;
            ws[row] = pre / (1.f + expf(-pre));     // silu -> conv_out
            f32x4 n; n.x = cs.y; n.y = cs.z; n.z = cs.w; n.w = acc;
            *reinterpret_cast<f32x4*>(out_conv + row * 4) = n;
        } else {
            ws[row] = acc;
        }
    }
}

// ---------------- Kernel 2: rec update, d-split: 128 blocks = (head, d-quarter) --
// block bx: hh = bx>>2, d-range [ (bx&3)*32, +32 ). 1024 threads:
// kkb = t>>3 (0..127 = full kk), dq4 = t&7 (d = D0 + dq4*4). One dwordx4 per thread.
// kv/core reductions over kk: wave shuffles (8 kk/wave) -> s_part[16][32] -> 32 threads.
// Writes UN-NORMALIZED core to ws+12352; RMS norm moved to k3 prologue.
__global__ __launch_bounds__(1024) void k2_rec(
    const float* __restrict__ ws,
    const float* __restrict__ rec_in,
    const float* __restrict__ dt_bias,
    const float* __restrict__ A_log,
    float* __restrict__ rec_out,
    float* __restrict__ core_out)        // ws + 12352
{
    __shared__ float s_k[128];
    __shared__ float s_q[128];
    __shared__ float s_part[16][32];
    __shared__ float s_delta[32];
    __shared__ float s_red[4];

    const int bx   = blockIdx.x;
    const int hh   = bx >> 2;
    const int D0   = (bx & 3) * 32;
    const int t    = threadIdx.x;
    const int lane = t & 63;
    const int wid  = t >> 6;             // 0..15
    const int kkb  = t >> 3;             // 0..127
    const int dq4  = t & 7;              // 0..7
    const int kh   = hh >> 1;            // key head (VPK = 2)

    const float bv    = ws[12288 + hh];
    const float av    = ws[12320 + hh];
    const float beta  = 1.f / (1.f + expf(-bv));
    const float x     = av + dt_bias[hh];
    const float sp    = fmaxf(x, 0.f) + log1pf(expf(-fabsf(x)));   // softplus
    const float decay = expf(-expf(A_log[hh]) * sp);

    // q/k l2-norm over full kk (threads 0..127), redundant across the 4 d-blocks
    float qr = 0.f, kr = 0.f;
    if (t < 128) {
        qr = ws[kh * 128 + t];
        kr = ws[KEY_DIM + kh * 128 + t];
        float sq = qr * qr, sk = kr * kr;
#pragma unroll
        for (int off = 32; off > 0; off >>= 1) {
            sq += __shfl_down(sq, off, 64);
            sk += __shfl_down(sk, off, 64);
        }
        if ((t & 63) == 0) { s_red[t >> 6] = sq; s_red[2 + (t >> 6)] = sk; }
    }
    __syncthreads();
    if (t < 128) {
        s_q[t] = qr * rsqrtf(s_red[0] + s_red[1] + 1e-6f) * 0.08838834764831845f;
        s_k[t] = kr * rsqrtf(s_red[2] + s_red[3] + 1e-6f);
    }
    __syncthreads();

    const size_t off0 = (size_t)hh * (DK * DV) + (size_t)kkb * DV + D0 + dq4 * 4;
    const f32x4 rv = *reinterpret_cast<const f32x4*>(rec_in + off0);
    const float sk = s_k[kkb];
    const float sq = s_q[kkb];

    // pass 1: kv partial over kk
    f32x4 kvp = rv * sk;
#pragma unroll
    for (int off = 32; off >= 8; off >>= 1) {
        kvp.x += __shfl_down(kvp.x, off, 64);
        kvp.y += __shfl_down(kvp.y, off, 64);
        kvp.z += __shfl_down(kvp.z, off, 64);
        kvp.w += __shfl_down(kvp.w, off, 64);
    }
    if (lane < 8) *reinterpret_cast<f32x4*>(&s_part[wid][lane * 4]) = kvp;
    __syncthreads();

    if (t < 32) {
        float kv = 0.f;
#pragma unroll
        for (int w = 0; w < 16; ++w) kv += s_part[w][t];
        kv *= decay;
        const float vv = ws[2 * KEY_DIM + hh * 128 + D0 + t];
        s_delta[t] = (vv - kv) * beta;
    }
    __syncthreads();

    // pass 2: rec_new + core partial
    const f32x4 dlt = *reinterpret_cast<const f32x4*>(&s_delta[dq4 * 4]);
    f32x4 r = rv * decay + dlt * sk;
    *reinterpret_cast<f32x4*>(rec_out + off0) = r;
    f32x4 cp = r * sq;
#pragma unroll
    for (int off = 32; off >= 8; off >>= 1) {
        cp.x += __shfl_down(cp.x, off, 64);
        cp.y += __shfl_down(cp.y, off, 64);
        cp.z += __shfl_down(cp.z, off, 64);
        cp.w += __shfl_down(cp.w, off, 64);
    }
    if (lane < 8) *reinterpret_cast<f32x4*>(&s_part[wid][lane * 4]) = cp;
    __syncthreads();

    if (t < 32) {
        float core = 0.f;
#pragma unroll
        for (int w = 0; w < 16; ++w) core += s_part[w][t];
        core_out[hh * 128 + D0 + t] = core;
    }
}

// ---------------- Kernel 3: prologue (RMS-norm + silu(z) -> LDS out_vec), then GEMV
__global__ __launch_bounds__(256) void k3_out(
    const float* __restrict__ Wout,       // 2048 x 4096
    const float* __restrict__ ws,         // core at +12352, z at +8192
    const float* __restrict__ norm_w,     // 128
    float* __restrict__ hidden_out)       // d_out[0:2048]
{
    __shared__ float s_ov[4096];          // 16 KB out_vec
    __shared__ float s_var[32];

    const float* core = ws + 12352;
    const float* z    = ws + 8192;
    const int t    = threadIdx.x;
    const int lane = t & 63;

    // per-head sum of squares: 8 threads per head, 16 elems each
    {
        float ss = 0.f;
#pragma unroll
        for (int q = 0; q < 4; ++q) {
            f32x4 c4 = *reinterpret_cast<const f32x4*>(core + t * 16 + q * 4);
            ss += c4.x * c4.x + c4.y * c4.y + c4.z * c4.z + c4.w * c4.w;
        }
        ss += __shfl_down(ss, 1, 64);
        ss += __shfl_down(ss, 2, 64);
        ss += __shfl_down(ss, 4, 64);
        if ((t & 7) == 0) s_var[t >> 3] = ss;
    }
    __syncthreads();

    // build out_vec = core * rsqrt(mean(core^2)+eps) * norm_w * silu(z)
#pragma unroll
    for (int c = 0; c < 4; ++c) {
        const int i = (c * 256 + t) * 4;
        f32x4 c4 = *reinterpret_cast<const f32x4*>(core + i);
        f32x4 z4 = *reinterpret_cast<const f32x4*>(z + i);
        f32x4 nw = *reinterpret_cast<const f32x4*>(norm_w + (i & 127));
        const float rstd = rsqrtf(s_var[i >> 7] * (1.f / 128.f) + 1e-6f);
        f32x4 ov;
        ov.x = c4.x * rstd * nw.x * (z4.x / (1.f + expf(-z4.x)));
        ov.y = c4.y * rstd * nw.y * (z4.y / (1.f + expf(-z4.y)));
        ov.z = c4.z * rstd * nw.z * (z4.z / (1.f + expf(-z4.z)));
        ov.w = c4.w * rstd * nw.w * (z4.w / (1.f + expf(-z4.w)));
        *reinterpret_cast<f32x4*>(&s_ov[i]) = ov;
    }
    __syncthreads();

    // GEMV: one wave per row
    const int row = blockIdx.x * 4 + (t >> 6);
    const float* wrow = Wout + (size_t)row * VALUE_DIM;
    float acc = 0.f;
#pragma unroll
    for (int i = 0; i < 16; ++i) {
        const int idx = (i * 64 + lane) * 4;
        f32x4 w4 = *reinterpret_cast<const f32x4*>(wrow + idx);
        f32x4 o4 = *reinterpret_cast<const f32x4*>(&s_ov[idx]);
        acc += w4.x * o4.x + w4.y * o4.y + w4.z * o4.z + w4.w * o4.w;
    }
#pragma unroll
    for (int off = 32; off > 0; off >>= 1)
        acc += __shfl_down(acc, off, 64);
    if (lane == 0) hidden_out[row] = acc;
}

extern "C" void kernel_launch(void* const* d_in, const int* in_sizes, int n_in,
                              void* d_out, int out_size, void* d_ws, size_t ws_size,
                              hipStream_t stream) {
    const float* hidden_in  = (const float*)d_in[0];
    const float* conv_state = (const float*)d_in[1];
    const float* rec_state  = (const float*)d_in[2];
    const float* W_qkv      = (const float*)d_in[3];
    const float* W_z        = (const float*)d_in[4];
    const float* W_b        = (const float*)d_in[5];
    const float* W_a        = (const float*)d_in[6];
    const float* W_out      = (const float*)d_in[7];
    const float* conv_w     = (const float*)d_in[8];
    const float* dt_bias    = (const float*)d_in[9];
    const float* A_log      = (const float*)d_in[10];
    const float* norm_w     = (const float*)d_in[11];

    float* out = (float*)d_out;
    float* ws  = (float*)d_ws;

    k1_gemv<<<TOTAL_ROWS / 4, 256, 0, stream>>>(hidden_in, W_qkv, W_z, W_b, W_a,
                                                conv_state, conv_w, ws, out + 2048);
    k2_rec<<<NUM_V * 4, 1024, 0, stream>>>(ws, rec_state, dt_bias, A_log,
                                           out + 2048 + CONV_DIM * 4, ws + 12352);
    k3_out<<<HDIM / 4, 256, 0, stream>>>(W_out, ws, norm_w, out);
}